// Round 13
// baseline (451.711 us; speedup 1.0000x reference)
//
#include <hip/hip_runtime.h>

// VQ-VAE Quantize: BN1d(batch stats) -> argmin L2 vs codebook -> gather + diff
// R13: dist_ct pipeline rework (math bit-frozen, R1/R7 chain):
//   - BK=16 double-buffered global_load_lds: loads for chunk t+1 issue before
//     compute of chunk t -> L2 latency hidden in-wave; 1 barrier/step.
//   - operands loaded as f32x2 (ds_read_b64) directly into the register pairs
//     pk_fma consumes -> no shufflevector movs.
//   - init_packed folded into embed_prep.
// Everything else (xnT precompute, XCD swizzle, atomicMin merge) = R12.

#define N_ROWS 65536
#define DIM 256
#define KCODES 1024
#define BN_EPS_F 1e-5f

#define STAT_BLOCKS 512      // 128 rows each
#define BM 128               // row tile
#define BNT 128              // code tile (8 tiles cover K)
#define E_BLOCKS 16384       // gather blocks: 4 rows each

typedef __attribute__((ext_vector_type(2))) float f32x2;

// ---------------- BN statistics: stage 1 ----------------
__global__ void bn_partial(const float* __restrict__ x, float* __restrict__ pSum,
                           float* __restrict__ pSq) {
    int t = threadIdx.x;
    int b = blockIdx.x;
    long base = (long)b * 128 * DIM;
    float s = 0.f, q = 0.f;
    for (int r = 0; r < 128; ++r) {
        float v = x[base + (long)r * DIM + t];
        s += v; q += v * v;
    }
    pSum[b * DIM + t] = s;
    pSq[b * DIM + t] = q;
}

// ---------------- BN statistics: stage 2 ----------------
__global__ void bn_finalize(const float* __restrict__ pSum, const float* __restrict__ pSq,
                            const float* __restrict__ gamma, const float* __restrict__ beta,
                            float* __restrict__ scale, float* __restrict__ shift) {
    int t = threadIdx.x;
    float s = 0.f, q = 0.f;
    for (int b = 0; b < STAT_BLOCKS; ++b) {
        s += pSum[b * DIM + t];
        q += pSq[b * DIM + t];
    }
    float mean = s * (1.0f / (float)N_ROWS);
    float var  = q * (1.0f / (float)N_ROWS) - mean * mean;  // biased var
    var = fmaxf(var, 0.f);
    float sc = gamma[t] * rsqrtf(var + BN_EPS_F);
    scale[t] = sc;
    shift[t] = beta[t] - mean * sc;
}

// ---------------- embed prep: transpose + norms; also init packed minima ----------------
__global__ void embed_prep(const float* __restrict__ embed, float* __restrict__ embedT,
                           float* __restrict__ enorm, unsigned long long* __restrict__ packed) {
    // init packed (runs after bn_finalize, so the pSum overlay is dead)
    #pragma unroll
    for (int i = 0; i < 8; ++i)
        packed[i * 8192 + blockIdx.x * 256 + threadIdx.x] = ~0ULL;

    __shared__ float T[32][33];
    __shared__ float ps[8][32];
    int tid = threadIdx.x;
    int tx = tid & 31;
    int ty = tid >> 5;
    int k0 = blockIdx.x * 32;
    float sq = 0.f;
    for (int d0 = 0; d0 < DIM; d0 += 32) {
        __syncthreads();
        #pragma unroll
        for (int p = 0; p < 4; ++p) {
            int dl = ty + p * 8;
            float v = embed[(long)(d0 + dl) * KCODES + k0 + tx];
            T[tx][dl] = v;
            sq += v * v;
        }
        __syncthreads();
        int kr = tid >> 3;
        int dc = (tid & 7) * 4;
        float4 w = make_float4(T[kr][dc], T[kr][dc + 1], T[kr][dc + 2], T[kr][dc + 3]);
        *(float4*)&embedT[(long)(k0 + kr) * DIM + d0 + dc] = w;
    }
    ps[ty][tx] = sq;
    __syncthreads();
    if (ty == 0) {
        float s = 0.f;
        #pragma unroll
        for (int i = 0; i < 8; ++i) s += ps[i][tx];
        enorm[k0 + tx] = s;
    }
}

// ---------------- xprep: xn = x*scale+shift, written TRANSPOSED xnT[d][row] ----------------
__global__ void xprep_t(const float* __restrict__ x, const float* __restrict__ scale,
                        const float* __restrict__ shift, float* __restrict__ xnT) {
    __shared__ float T[64][65];
    int t = threadIdx.x;
    int rb = blockIdx.x >> 2;        // row tile (64 rows)
    int db = blockIdx.x & 3;         // d tile (64 d)
    {
        int c4 = t & 15;
        int r  = t >> 4;
        float4 scv = *(const float4*)&scale[db * 64 + c4 * 4];
        float4 shv = *(const float4*)&shift[db * 64 + c4 * 4];
        #pragma unroll
        for (int p = 0; p < 4; ++p) {
            int rl = r + p * 16;
            long row = (long)rb * 64 + rl;
            float4 v = *(const float4*)&x[row * DIM + db * 64 + c4 * 4];
            T[c4 * 4 + 0][rl] = v.x * scv.x + shv.x;
            T[c4 * 4 + 1][rl] = v.y * scv.y + shv.y;
            T[c4 * 4 + 2][rl] = v.z * scv.z + shv.z;
            T[c4 * 4 + 3][rl] = v.w * scv.w + shv.w;
        }
    }
    __syncthreads();
    {
        int rq = t & 15;
        int dl = t >> 4;
        #pragma unroll
        for (int p = 0; p < 4; ++p) {
            int dloc = dl + p * 16;
            float4 w = make_float4(T[dloc][rq * 4], T[dloc][rq * 4 + 1],
                                   T[dloc][rq * 4 + 2], T[dloc][rq * 4 + 3]);
            *(float4*)&xnT[(long)(db * 64 + dloc) * N_ROWS + (long)rb * 64 + rq * 4] = w;
        }
    }
}

// ---------------- fused distance GEMM + argmin (one 128-code tile) ----------------
// score(n,k) = ||e_k||^2 - 2 * dot(xn,e_k); chain bit-frozen (R1/R7).
// blockIdx swizzle: ct = (phys>>3)&7, rt = (phys&7) | ((phys>>6)<<3).
// Double-buffered: LB = 2 x (A[16][128] + B[16][128]) = 32 KB.
__global__ __launch_bounds__(256, 5) void dist_ct(
    const float* __restrict__ xnT, const float* __restrict__ embed,
    const float* __restrict__ enorm, unsigned long long* __restrict__ packed) {
    __shared__ __attribute__((aligned(16))) float LB[8192];

    int tid = threadIdx.x;
    int tx = tid & 15;       // code group 0..15
    int ty = tid >> 4;       // row group 0..15
    int phys = blockIdx.x;
    int ct = (phys >> 3) & 7;
    long rt = (long)((phys & 7) | ((phys >> 6) << 3));
    long row0 = rt * BM;

    f32x2 acc2[8][4];
    #pragma unroll
    for (int i = 0; i < 8; ++i)
        #pragma unroll
        for (int jp = 0; jp < 4; ++jp) acc2[i][jp] = (f32x2){0.f, 0.f};

    // staging: 1024 x 16B chunks per step (A 512 + B 512), 4 per thread
    // slot = i*256 + tid; i<2 -> A, else B; r=(slot>>5)&15, c=slot&31
    #define STAGE(ck, buf)                                                              \
        {                                                                               \
            _Pragma("unroll")                                                           \
            for (int i = 0; i < 4; ++i) {                                               \
                int slot = i * 256 + tid;                                               \
                int r = (slot >> 5) & 15;                                               \
                int c = slot & 31;                                                      \
                const float* src = (i < 2)                                              \
                    ? xnT + (long)((ck) * 16 + r) * N_ROWS + row0 + c * 4               \
                    : embed + (long)((ck) * 16 + r) * KCODES + ct * BNT + c * 4;        \
                __builtin_amdgcn_global_load_lds(                                       \
                    (const __attribute__((address_space(1))) unsigned int*)src,         \
                    (__attribute__((address_space(3))) unsigned int*)(LB + (buf) * 4096 + slot * 4), \
                    16, 0, 0);                                                          \
            }                                                                           \
        }

    STAGE(0, 0);
    __syncthreads();

    for (int ck = 0; ck < 16; ++ck) {
        int cur = ck & 1;
        if (ck < 15) STAGE(ck + 1, cur ^ 1);
        const float* As = LB + cur * 4096;
        const float* Bs = As + 2048;
        #pragma unroll
        for (int kk = 0; kk < 16; ++kk) {
            // operands born as f32x2 pairs (ds_read_b64) -> no extraction movs
            f32x2 ap0 = *(const f32x2*)&As[kk * 128 + ty * 8];
            f32x2 ap1 = *(const f32x2*)&As[kk * 128 + ty * 8 + 2];
            f32x2 ap2 = *(const f32x2*)&As[kk * 128 + ty * 8 + 4];
            f32x2 ap3 = *(const f32x2*)&As[kk * 128 + ty * 8 + 6];
            f32x2 bp0 = *(const f32x2*)&Bs[kk * 128 + tx * 4];
            f32x2 bp1 = *(const f32x2*)&Bs[kk * 128 + tx * 4 + 2];
            f32x2 bp2 = *(const f32x2*)&Bs[kk * 128 + 64 + tx * 4];
            f32x2 bp3 = *(const f32x2*)&Bs[kk * 128 + 64 + tx * 4 + 2];
            f32x2 ap[4] = {ap0, ap1, ap2, ap3};
            f32x2 bp[4] = {bp0, bp1, bp2, bp3};
            #pragma unroll
            for (int ih = 0; ih < 4; ++ih) {
                #pragma unroll
                for (int jp = 0; jp < 4; ++jp) {
                    asm("v_pk_fma_f32 %0, %1, %2, %0 op_sel:[0,0,0] op_sel_hi:[1,0,1]"
                        : "+v"(acc2[2 * ih][jp]) : "v"(bp[jp]), "v"(ap[ih]));
                    asm("v_pk_fma_f32 %0, %1, %2, %0 op_sel:[0,1,0] op_sel_hi:[1,1,1]"
                        : "+v"(acc2[2 * ih + 1][jp]) : "v"(bp[jp]), "v"(ap[ih]));
                }
            }
        }
        __syncthreads();
    }

    // ---- epilogue: scores + per-ct candidate + deterministic global merge
    float4 en0 = *(const float4*)&enorm[ct * BNT + tx * 4];
    float4 en1 = *(const float4*)&enorm[ct * BNT + 64 + tx * 4];
    float en[8] = {en0.x, en0.y, en0.z, en0.w, en1.x, en1.y, en1.z, en1.w};
    int col0 = ct * BNT + tx * 4;
    int col1 = ct * BNT + 64 + tx * 4;
    #pragma unroll
    for (int i = 0; i < 8; ++i) {
        float bv = 3.4e38f;
        int bi = 0;
        #pragma unroll
        for (int j = 0; j < 8; ++j) {
            float d = (j & 1) ? acc2[i][j >> 1].y : acc2[i][j >> 1].x;
            float s = en[j] - 2.0f * d;
            int col = (j < 4) ? (col0 + j) : (col1 + (j - 4));
            if (s < bv) { bv = s; bi = col; }           // ascending cols: first-min kept
        }
        #pragma unroll
        for (int m = 1; m < 16; m <<= 1) {
            float ov = __shfl_xor(bv, m);
            int   oi = __shfl_xor(bi, m);
            if (ov < bv || (ov == bv && oi < bi)) { bv = ov; bi = oi; }
        }
        if (tx == 0) {
            float t = bv + 0.0f;                         // fold -0.0 -> +0.0
            unsigned ub = __float_as_uint(t);
            unsigned enc = (t >= 0.f) ? (ub ^ 0x80000000u) : ~ub;  // order-preserving
            unsigned long long pk = ((unsigned long long)enc << 32) | (unsigned)bi;
            atomicMin(&packed[row0 + ty * 8 + i], pk);   // lexicographic (score, idx) min
        }
    }
}

// ---------------- gather codebook rows + diff partials ----------------
__global__ void gather_out(const float* __restrict__ x, const float* __restrict__ embedT,
                           const float* __restrict__ scale, const float* __restrict__ shift,
                           const unsigned long long* __restrict__ packed, float* __restrict__ out,
                           float* __restrict__ diffPart) {
    __shared__ float wsum[4];
    int tid = threadIdx.x;
    int wave = tid >> 6, lane = tid & 63;
    long row = (long)blockIdx.x * 4 + wave;
    int k = (int)(unsigned)(packed[row] & 0xFFFFFFFFULL);
    int d0 = lane * 4;
    float4 q  = *(const float4*)&embedT[(long)k * DIM + d0];
    float4 xv = *(const float4*)&x[row * DIM + d0];
    float4 sc = *(const float4*)&scale[d0];
    float4 sh = *(const float4*)&shift[d0];
    float xn0 = xv.x * sc.x + sh.x;
    float xn1 = xv.y * sc.y + sh.y;
    float xn2 = xv.z * sc.z + sh.z;
    float xn3 = xv.w * sc.w + sh.w;
    *(float4*)&out[row * DIM + d0] = q;
    float d0f = q.x - xn0, d1f = q.y - xn1, d2f = q.z - xn2, d3f = q.w - xn3;
    float dsq = d0f * d0f + d1f * d1f + d2f * d2f + d3f * d3f;
    #pragma unroll
    for (int m = 32; m; m >>= 1) dsq += __shfl_xor(dsq, m);
    if (lane == 0) wsum[wave] = dsq;
    __syncthreads();
    if (tid == 0) diffPart[blockIdx.x] = wsum[0] + wsum[1] + wsum[2] + wsum[3];
}

// ---------------- final diff reduce ----------------
__global__ void diff_final(const float* __restrict__ diffPart, float* __restrict__ outDiff) {
    __shared__ float s[256];
    int tid = threadIdx.x;
    float a = 0.f;
    for (int i = tid; i < E_BLOCKS; i += 256) a += diffPart[i];
    s[tid] = a;
    __syncthreads();
    for (int st = 128; st; st >>= 1) {
        if (tid < st) s[tid] += s[tid + st];
        __syncthreads();
    }
    if (tid == 0) outDiff[0] = s[0] * (1.0f / (float)(N_ROWS * DIM));
}

extern "C" void kernel_launch(void* const* d_in, const int* in_sizes, int n_in,
                              void* d_out, int out_size, void* d_ws, size_t ws_size,
                              hipStream_t stream) {
    const float* x     = (const float*)d_in[0];
    const float* embed = (const float*)d_in[1];
    const float* gamma = (const float*)d_in[2];
    const float* beta  = (const float*)d_in[3];
    float* out = (float*)d_out;

    // xnT (fp32, transposed, 64 MB) lives in d_out; gather rewrites it after dist.
    float* xnT = (float*)d_out;

    // ws layout — same proven extent (2,430,976 B)
    char* w = (char*)d_ws;
    float* pSum    = (float*)(w);                 // [0, 512K)   bn only
    float* pSq     = (float*)(w + 524288);        // [512K, 1M)  bn only
    unsigned long long* packed = (unsigned long long*)(w);  // 512K, overlays dead pSum
    float* scale   = (float*)(w + 1048576);       // 1 KB
    float* shift   = (float*)(w + 1049600);       // 1 KB
    float* embedT  = (float*)(w + 1050624);       // 1 MB
    float* enorm   = (float*)(w + 2099200);       // 4 KB
    float* diffPart= (float*)(w + 2365440);       // 64 KB -> ends 2430976

    bn_partial<<<STAT_BLOCKS, 256, 0, stream>>>(x, pSum, pSq);
    bn_finalize<<<1, 256, 0, stream>>>(pSum, pSq, gamma, beta, scale, shift);
    embed_prep<<<KCODES / 32, 256, 0, stream>>>(embed, embedT, enorm, packed);
    xprep_t<<<(N_ROWS / 64) * (DIM / 64), 256, 0, stream>>>(x, scale, shift, xnT);
    dist_ct<<<(N_ROWS / BM) * 8, 256, 0, stream>>>(xnT, embed, enorm, packed);
    gather_out<<<E_BLOCKS, 256, 0, stream>>>(x, embedT, scale, shift, packed, out, diffPart);
    diff_final<<<1, 256, 0, stream>>>(diffPart, out + (long)N_ROWS * DIM);
}

// Round 14
// 428.420 us; speedup vs baseline: 1.0544x; 1.0544x over previous
//
#include <hip/hip_runtime.h>

// VQ-VAE Quantize: BN1d(batch stats) -> argmin L2 vs codebook -> gather + diff
// R14: revert R13's double-buffer (regressed: compiler drains vmcnt at every
// barrier). dist_ct = R12's proven structure + incremental staging pointers.
// Peripheral: embed_prep+xprep fused into one kernel; gather 8 rows/block.
// Frozen-math invariants (R1/R7): bn structure, normalize expressions, per
// (row,code) sequential fp32 chain over d ascending, argmin ties, merge.

#define N_ROWS 65536
#define DIM 256
#define KCODES 1024
#define BN_EPS_F 1e-5f

#define STAT_BLOCKS 512      // 128 rows each
#define BM 128               // row tile
#define BNT 128              // code tile (8 tiles cover K)
#define BK 32                // d-chunk
#define G_BLOCKS 8192        // gather blocks: 8 rows each

typedef __attribute__((ext_vector_type(2))) float f32x2;
typedef __attribute__((ext_vector_type(4))) float f32x4v;

// ---------------- BN statistics: stage 1 (frozen) ----------------
__global__ void bn_partial(const float* __restrict__ x, float* __restrict__ pSum,
                           float* __restrict__ pSq) {
    int t = threadIdx.x;
    int b = blockIdx.x;
    long base = (long)b * 128 * DIM;
    float s = 0.f, q = 0.f;
    for (int r = 0; r < 128; ++r) {
        float v = x[base + (long)r * DIM + t];
        s += v; q += v * v;
    }
    pSum[b * DIM + t] = s;
    pSq[b * DIM + t] = q;
}

// ---------------- BN statistics: stage 2 (frozen) ----------------
__global__ void bn_finalize(const float* __restrict__ pSum, const float* __restrict__ pSq,
                            const float* __restrict__ gamma, const float* __restrict__ beta,
                            float* __restrict__ scale, float* __restrict__ shift) {
    int t = threadIdx.x;
    float s = 0.f, q = 0.f;
    for (int b = 0; b < STAT_BLOCKS; ++b) {
        s += pSum[b * DIM + t];
        q += pSq[b * DIM + t];
    }
    float mean = s * (1.0f / (float)N_ROWS);
    float var  = q * (1.0f / (float)N_ROWS) - mean * mean;  // biased var
    var = fmaxf(var, 0.f);
    float sc = gamma[t] * rsqrtf(var + BN_EPS_F);
    scale[t] = sc;
    shift[t] = beta[t] - mean * sc;
}

// ---------------- fused prep: blocks 0..31 = embed prep (+packed init),
//                  blocks 32.. = xnT transpose-normalize ----------------
__global__ void prep_fused(const float* __restrict__ embed, float* __restrict__ embedT,
                           float* __restrict__ enorm, unsigned long long* __restrict__ packed,
                           const float* __restrict__ x, const float* __restrict__ scale,
                           const float* __restrict__ shift, float* __restrict__ xnT) {
    __shared__ float SH[64 * 65];
    int tid = threadIdx.x;
    if (blockIdx.x < 32) {
        // ---- embed_prep body (R12-verbatim math) + packed init
        #pragma unroll
        for (int i = 0; i < 8; ++i)
            packed[i * 8192 + blockIdx.x * 256 + tid] = ~0ULL;
        float (*T)[33]  = (float(*)[33])SH;
        float (*ps)[32] = (float(*)[32])(SH + 32 * 33);
        int tx = tid & 31;
        int ty = tid >> 5;
        int k0 = blockIdx.x * 32;
        float sq = 0.f;
        for (int d0 = 0; d0 < DIM; d0 += 32) {
            __syncthreads();
            #pragma unroll
            for (int p = 0; p < 4; ++p) {
                int dl = ty + p * 8;
                float v = embed[(long)(d0 + dl) * KCODES + k0 + tx];
                T[tx][dl] = v;
                sq += v * v;
            }
            __syncthreads();
            int kr = tid >> 3;
            int dc = (tid & 7) * 4;
            float4 w = make_float4(T[kr][dc], T[kr][dc + 1], T[kr][dc + 2], T[kr][dc + 3]);
            *(float4*)&embedT[(long)(k0 + kr) * DIM + d0 + dc] = w;
        }
        ps[ty][tx] = sq;
        __syncthreads();
        if (ty == 0) {
            float s = 0.f;
            #pragma unroll
            for (int i = 0; i < 8; ++i) s += ps[i][tx];
            enorm[k0 + tx] = s;
        }
    } else {
        // ---- xprep_t body (normalize expression textually frozen)
        float (*T)[65] = (float(*)[65])SH;
        int bb = blockIdx.x - 32;
        int rb = bb >> 2;        // row tile (64 rows)
        int db = bb & 3;         // d tile (64 d)
        {
            int c4 = tid & 15;
            int r  = tid >> 4;
            float4 scv = *(const float4*)&scale[db * 64 + c4 * 4];
            float4 shv = *(const float4*)&shift[db * 64 + c4 * 4];
            #pragma unroll
            for (int p = 0; p < 4; ++p) {
                int rl = r + p * 16;
                long row = (long)rb * 64 + rl;
                float4 v = *(const float4*)&x[row * DIM + db * 64 + c4 * 4];
                T[c4 * 4 + 0][rl] = v.x * scv.x + shv.x;
                T[c4 * 4 + 1][rl] = v.y * scv.y + shv.y;
                T[c4 * 4 + 2][rl] = v.z * scv.z + shv.z;
                T[c4 * 4 + 3][rl] = v.w * scv.w + shv.w;
            }
        }
        __syncthreads();
        {
            int rq = tid & 15;
            int dl = tid >> 4;
            #pragma unroll
            for (int p = 0; p < 4; ++p) {
                int dloc = dl + p * 16;
                float4 w = make_float4(T[dloc][rq * 4], T[dloc][rq * 4 + 1],
                                       T[dloc][rq * 4 + 2], T[dloc][rq * 4 + 3]);
                *(float4*)&xnT[(long)(db * 64 + dloc) * N_ROWS + (long)rb * 64 + rq * 4] = w;
            }
        }
    }
}

// ---------------- fused distance GEMM + argmin (one 128-code tile) ----------------
// score(n,k) = ||e_k||^2 - 2 * dot(xn,e_k); chain bit-frozen (R1/R7).
// blockIdx swizzle: ct = (phys>>3)&7, rt = (phys&7) | ((phys>>6)<<3).
// R12 structure: BK=32, global_load_lds staging, pk_fma compute, 2 barriers/dk.
__global__ __launch_bounds__(256, 5) void dist_ct(
    const float* __restrict__ xnT, const float* __restrict__ embed,
    const float* __restrict__ enorm, unsigned long long* __restrict__ packed) {
    __shared__ __attribute__((aligned(16))) float LB[8192];   // As[32][128] + Bs[32][128]
    float* As = LB;
    float* Bs = LB + 4096;

    int tid = threadIdx.x;
    int tx = tid & 15;       // code group 0..15
    int ty = tid >> 4;       // row group 0..15
    int phys = blockIdx.x;
    int ct = (phys >> 3) & 7;
    long rt = (long)((phys & 7) | ((phys >> 6) << 3));
    long row0 = rt * BM;

    f32x2 acc2[8][4];
    #pragma unroll
    for (int i = 0; i < 8; ++i)
        #pragma unroll
        for (int jp = 0; jp < 4; ++jp) acc2[i][jp] = (f32x2){0.f, 0.f};

    int dpart = tid >> 5;    // 0..7  (d' sub-row per load)
    int cpart = tid & 31;    // 16B chunk along the 128-wide row

    // incremental staging pointers (same addresses as R12, less per-dk VALU)
    const float* aPtr = xnT + (long)dpart * N_ROWS + row0 + cpart * 4;
    const float* bPtr = embed + (long)dpart * KCODES + ct * BNT + cpart * 4;

    for (int dk = 0; dk < DIM; dk += BK) {
        __syncthreads();  // previous compute done before restaging
        #pragma unroll
        for (int i = 0; i < 4; ++i) {
            __builtin_amdgcn_global_load_lds(
                (const __attribute__((address_space(1))) unsigned int*)(aPtr + (long)i * 8 * N_ROWS),
                (__attribute__((address_space(3))) unsigned int*)(As + (i * 256 + tid) * 4),
                16, 0, 0);
        }
        #pragma unroll
        for (int i = 0; i < 4; ++i) {
            __builtin_amdgcn_global_load_lds(
                (const __attribute__((address_space(1))) unsigned int*)(bPtr + (long)i * 8 * KCODES),
                (__attribute__((address_space(3))) unsigned int*)(Bs + (i * 256 + tid) * 4),
                16, 0, 0);
        }
        __syncthreads();
        aPtr += (long)BK * N_ROWS;
        bPtr += (long)BK * KCODES;
        // ---- compute: 8x8 micro-tile via v_pk_fma_f32 (bit-frozen chains)
        #pragma unroll 8
        for (int kk = 0; kk < BK; ++kk) {
            f32x4v a0 = *(const f32x4v*)&As[kk * 128 + ty * 8];
            f32x4v a1 = *(const f32x4v*)&As[kk * 128 + ty * 8 + 4];
            f32x4v b0 = *(const f32x4v*)&Bs[kk * 128 + tx * 4];
            f32x4v b1 = *(const f32x4v*)&Bs[kk * 128 + 64 + tx * 4];
            f32x2 bp[4] = {
                __builtin_shufflevector(b0, b0, 0, 1),
                __builtin_shufflevector(b0, b0, 2, 3),
                __builtin_shufflevector(b1, b1, 0, 1),
                __builtin_shufflevector(b1, b1, 2, 3)
            };
            f32x2 ap[4] = {
                __builtin_shufflevector(a0, a0, 0, 1),
                __builtin_shufflevector(a0, a0, 2, 3),
                __builtin_shufflevector(a1, a1, 0, 1),
                __builtin_shufflevector(a1, a1, 2, 3)
            };
            #pragma unroll
            for (int ih = 0; ih < 4; ++ih) {
                #pragma unroll
                for (int jp = 0; jp < 4; ++jp) {
                    asm("v_pk_fma_f32 %0, %1, %2, %0 op_sel:[0,0,0] op_sel_hi:[1,0,1]"
                        : "+v"(acc2[2 * ih][jp]) : "v"(bp[jp]), "v"(ap[ih]));
                    asm("v_pk_fma_f32 %0, %1, %2, %0 op_sel:[0,1,0] op_sel_hi:[1,1,1]"
                        : "+v"(acc2[2 * ih + 1][jp]) : "v"(bp[jp]), "v"(ap[ih]));
                }
            }
        }
    }
    // ---- epilogue: scores + per-ct candidate + deterministic global merge
    float4 en0 = *(const float4*)&enorm[ct * BNT + tx * 4];
    float4 en1 = *(const float4*)&enorm[ct * BNT + 64 + tx * 4];
    float en[8] = {en0.x, en0.y, en0.z, en0.w, en1.x, en1.y, en1.z, en1.w};
    int col0 = ct * BNT + tx * 4;
    int col1 = ct * BNT + 64 + tx * 4;
    #pragma unroll
    for (int i = 0; i < 8; ++i) {
        float bv = 3.4e38f;
        int bi = 0;
        #pragma unroll
        for (int j = 0; j < 8; ++j) {
            float d = (j & 1) ? acc2[i][j >> 1].y : acc2[i][j >> 1].x;
            float s = en[j] - 2.0f * d;
            int col = (j < 4) ? (col0 + j) : (col1 + (j - 4));
            if (s < bv) { bv = s; bi = col; }           // ascending cols: first-min kept
        }
        #pragma unroll
        for (int m = 1; m < 16; m <<= 1) {
            float ov = __shfl_xor(bv, m);
            int   oi = __shfl_xor(bi, m);
            if (ov < bv || (ov == bv && oi < bi)) { bv = ov; bi = oi; }
        }
        if (tx == 0) {
            float t = bv + 0.0f;                         // fold -0.0 -> +0.0
            unsigned ub = __float_as_uint(t);
            unsigned enc = (t >= 0.f) ? (ub ^ 0x80000000u) : ~ub;  // order-preserving
            unsigned long long pk = ((unsigned long long)enc << 32) | (unsigned)bi;
            atomicMin(&packed[row0 + ty * 8 + i], pk);   // lexicographic (score, idx) min
        }
    }
}

// ---------------- gather codebook rows + diff partials (8 rows/block) ----------------
__global__ void gather_out(const float* __restrict__ x, const float* __restrict__ embedT,
                           const float* __restrict__ scale, const float* __restrict__ shift,
                           const unsigned long long* __restrict__ packed, float* __restrict__ out,
                           float* __restrict__ diffPart) {
    __shared__ float wsum[4];
    int tid = threadIdx.x;
    int wave = tid >> 6, lane = tid & 63;
    int d0 = lane * 4;
    float4 sc = *(const float4*)&scale[d0];
    float4 sh = *(const float4*)&shift[d0];
    float acc = 0.f;
    #pragma unroll
    for (int r2 = 0; r2 < 2; ++r2) {
        long row = (long)blockIdx.x * 8 + wave * 2 + r2;
        int k = (int)(unsigned)(packed[row] & 0xFFFFFFFFULL);
        float4 q  = *(const float4*)&embedT[(long)k * DIM + d0];
        float4 xv = *(const float4*)&x[row * DIM + d0];
        float xn0 = xv.x * sc.x + sh.x;
        float xn1 = xv.y * sc.y + sh.y;
        float xn2 = xv.z * sc.z + sh.z;
        float xn3 = xv.w * sc.w + sh.w;
        *(float4*)&out[row * DIM + d0] = q;
        float d0f = q.x - xn0, d1f = q.y - xn1, d2f = q.z - xn2, d3f = q.w - xn3;
        float dsq = d0f * d0f + d1f * d1f + d2f * d2f + d3f * d3f;
        #pragma unroll
        for (int m = 32; m; m >>= 1) dsq += __shfl_xor(dsq, m);
        acc += dsq;
    }
    if (lane == 0) wsum[wave] = acc;
    __syncthreads();
    if (tid == 0) diffPart[blockIdx.x] = wsum[0] + wsum[1] + wsum[2] + wsum[3];
}

// ---------------- final diff reduce ----------------
__global__ void diff_final(const float* __restrict__ diffPart, float* __restrict__ outDiff) {
    __shared__ float s[256];
    int tid = threadIdx.x;
    float a = 0.f;
    for (int i = tid; i < G_BLOCKS; i += 256) a += diffPart[i];
    s[tid] = a;
    __syncthreads();
    for (int st = 128; st; st >>= 1) {
        if (tid < st) s[tid] += s[tid + st];
        __syncthreads();
    }
    if (tid == 0) outDiff[0] = s[0] * (1.0f / (float)(N_ROWS * DIM));
}

extern "C" void kernel_launch(void* const* d_in, const int* in_sizes, int n_in,
                              void* d_out, int out_size, void* d_ws, size_t ws_size,
                              hipStream_t stream) {
    const float* x     = (const float*)d_in[0];
    const float* embed = (const float*)d_in[1];
    const float* gamma = (const float*)d_in[2];
    const float* beta  = (const float*)d_in[3];
    float* out = (float*)d_out;

    // xnT (fp32, transposed, 64 MB) lives in d_out; gather rewrites it after dist.
    float* xnT = (float*)d_out;

    // ws layout — same proven extent (2,430,976 B)
    char* w = (char*)d_ws;
    float* pSum    = (float*)(w);                 // [0, 512K)   bn only
    float* pSq     = (float*)(w + 524288);        // [512K, 1M)  bn only
    unsigned long long* packed = (unsigned long long*)(w);  // 512K, overlays dead pSum
    float* scale   = (float*)(w + 1048576);       // 1 KB
    float* shift   = (float*)(w + 1049600);       // 1 KB
    float* embedT  = (float*)(w + 1050624);       // 1 MB
    float* enorm   = (float*)(w + 2099200);       // 4 KB
    float* diffPart= (float*)(w + 2365440);       // 32 KB -> ends 2398208

    bn_partial<<<STAT_BLOCKS, 256, 0, stream>>>(x, pSum, pSq);
    bn_finalize<<<1, 256, 0, stream>>>(pSum, pSq, gamma, beta, scale, shift);
    prep_fused<<<32 + (N_ROWS / 64) * (DIM / 64), 256, 0, stream>>>(
        embed, embedT, enorm, packed, x, scale, shift, xnT);
    dist_ct<<<(N_ROWS / BM) * 8, 256, 0, stream>>>(xnT, embed, enorm, packed);
    gather_out<<<G_BLOCKS, 256, 0, stream>>>(x, embedT, scale, shift, packed, out, diffPart);
    diff_final<<<1, 256, 0, stream>>>(diffPart, out + (long)N_ROWS * DIM);
}

// Round 15
// 427.784 us; speedup vs baseline: 1.0559x; 1.0015x over previous
//
#include <hip/hip_runtime.h>

// VQ-VAE Quantize: BN1d(batch stats) -> argmin L2 vs codebook -> gather + diff
// R15: R14 with ONE change (clean A/B): pk_fma operands loaded directly as
// f32x2 (ds_read_b64) instead of b128+shufflevector — tests whether the
// 181k-cycle/SIMD VALU-busy gap is operand-copy movs. Same LDS-pipe cycles,
// same addresses, same bit-frozen fp32 chains (R1/R7), same everything else.

#define N_ROWS 65536
#define DIM 256
#define KCODES 1024
#define BN_EPS_F 1e-5f

#define STAT_BLOCKS 512      // 128 rows each
#define BM 128               // row tile
#define BNT 128              // code tile (8 tiles cover K)
#define BK 32                // d-chunk
#define G_BLOCKS 8192        // gather blocks: 8 rows each

typedef __attribute__((ext_vector_type(2))) float f32x2;

// ---------------- BN statistics: stage 1 (frozen) ----------------
__global__ void bn_partial(const float* __restrict__ x, float* __restrict__ pSum,
                           float* __restrict__ pSq) {
    int t = threadIdx.x;
    int b = blockIdx.x;
    long base = (long)b * 128 * DIM;
    float s = 0.f, q = 0.f;
    for (int r = 0; r < 128; ++r) {
        float v = x[base + (long)r * DIM + t];
        s += v; q += v * v;
    }
    pSum[b * DIM + t] = s;
    pSq[b * DIM + t] = q;
}

// ---------------- BN statistics: stage 2 (frozen) ----------------
__global__ void bn_finalize(const float* __restrict__ pSum, const float* __restrict__ pSq,
                            const float* __restrict__ gamma, const float* __restrict__ beta,
                            float* __restrict__ scale, float* __restrict__ shift) {
    int t = threadIdx.x;
    float s = 0.f, q = 0.f;
    for (int b = 0; b < STAT_BLOCKS; ++b) {
        s += pSum[b * DIM + t];
        q += pSq[b * DIM + t];
    }
    float mean = s * (1.0f / (float)N_ROWS);
    float var  = q * (1.0f / (float)N_ROWS) - mean * mean;  // biased var
    var = fmaxf(var, 0.f);
    float sc = gamma[t] * rsqrtf(var + BN_EPS_F);
    scale[t] = sc;
    shift[t] = beta[t] - mean * sc;
}

// ---------------- fused prep: blocks 0..31 = embed prep (+packed init),
//                  blocks 32.. = xnT transpose-normalize ----------------
__global__ void prep_fused(const float* __restrict__ embed, float* __restrict__ embedT,
                           float* __restrict__ enorm, unsigned long long* __restrict__ packed,
                           const float* __restrict__ x, const float* __restrict__ scale,
                           const float* __restrict__ shift, float* __restrict__ xnT) {
    __shared__ float SH[64 * 65];
    int tid = threadIdx.x;
    if (blockIdx.x < 32) {
        #pragma unroll
        for (int i = 0; i < 8; ++i)
            packed[i * 8192 + blockIdx.x * 256 + tid] = ~0ULL;
        float (*T)[33]  = (float(*)[33])SH;
        float (*ps)[32] = (float(*)[32])(SH + 32 * 33);
        int tx = tid & 31;
        int ty = tid >> 5;
        int k0 = blockIdx.x * 32;
        float sq = 0.f;
        for (int d0 = 0; d0 < DIM; d0 += 32) {
            __syncthreads();
            #pragma unroll
            for (int p = 0; p < 4; ++p) {
                int dl = ty + p * 8;
                float v = embed[(long)(d0 + dl) * KCODES + k0 + tx];
                T[tx][dl] = v;
                sq += v * v;
            }
            __syncthreads();
            int kr = tid >> 3;
            int dc = (tid & 7) * 4;
            float4 w = make_float4(T[kr][dc], T[kr][dc + 1], T[kr][dc + 2], T[kr][dc + 3]);
            *(float4*)&embedT[(long)(k0 + kr) * DIM + d0 + dc] = w;
        }
        ps[ty][tx] = sq;
        __syncthreads();
        if (ty == 0) {
            float s = 0.f;
            #pragma unroll
            for (int i = 0; i < 8; ++i) s += ps[i][tx];
            enorm[k0 + tx] = s;
        }
    } else {
        float (*T)[65] = (float(*)[65])SH;
        int bb = blockIdx.x - 32;
        int rb = bb >> 2;        // row tile (64 rows)
        int db = bb & 3;         // d tile (64 d)
        {
            int c4 = tid & 15;
            int r  = tid >> 4;
            float4 scv = *(const float4*)&scale[db * 64 + c4 * 4];
            float4 shv = *(const float4*)&shift[db * 64 + c4 * 4];
            #pragma unroll
            for (int p = 0; p < 4; ++p) {
                int rl = r + p * 16;
                long row = (long)rb * 64 + rl;
                float4 v = *(const float4*)&x[row * DIM + db * 64 + c4 * 4];
                T[c4 * 4 + 0][rl] = v.x * scv.x + shv.x;
                T[c4 * 4 + 1][rl] = v.y * scv.y + shv.y;
                T[c4 * 4 + 2][rl] = v.z * scv.z + shv.z;
                T[c4 * 4 + 3][rl] = v.w * scv.w + shv.w;
            }
        }
        __syncthreads();
        {
            int rq = tid & 15;
            int dl = tid >> 4;
            #pragma unroll
            for (int p = 0; p < 4; ++p) {
                int dloc = dl + p * 16;
                float4 w = make_float4(T[dloc][rq * 4], T[dloc][rq * 4 + 1],
                                       T[dloc][rq * 4 + 2], T[dloc][rq * 4 + 3]);
                *(float4*)&xnT[(long)(db * 64 + dloc) * N_ROWS + (long)rb * 64 + rq * 4] = w;
            }
        }
    }
}

// ---------------- fused distance GEMM + argmin (one 128-code tile) ----------------
// score(n,k) = ||e_k||^2 - 2 * dot(xn,e_k); chain bit-frozen (R1/R7).
// blockIdx swizzle: ct = (phys>>3)&7, rt = (phys&7) | ((phys>>6)<<3).
__global__ __launch_bounds__(256, 5) void dist_ct(
    const float* __restrict__ xnT, const float* __restrict__ embed,
    const float* __restrict__ enorm, unsigned long long* __restrict__ packed) {
    __shared__ __attribute__((aligned(16))) float LB[8192];   // As[32][128] + Bs[32][128]
    float* As = LB;
    float* Bs = LB + 4096;

    int tid = threadIdx.x;
    int tx = tid & 15;       // code group 0..15
    int ty = tid >> 4;       // row group 0..15
    int phys = blockIdx.x;
    int ct = (phys >> 3) & 7;
    long rt = (long)((phys & 7) | ((phys >> 6) << 3));
    long row0 = rt * BM;

    f32x2 acc2[8][4];
    #pragma unroll
    for (int i = 0; i < 8; ++i)
        #pragma unroll
        for (int jp = 0; jp < 4; ++jp) acc2[i][jp] = (f32x2){0.f, 0.f};

    int dpart = tid >> 5;    // 0..7  (d' sub-row per load)
    int cpart = tid & 31;    // 16B chunk along the 128-wide row

    const float* aPtr = xnT + (long)dpart * N_ROWS + row0 + cpart * 4;
    const float* bPtr = embed + (long)dpart * KCODES + ct * BNT + cpart * 4;

    for (int dk = 0; dk < DIM; dk += BK) {
        __syncthreads();  // previous compute done before restaging
        #pragma unroll
        for (int i = 0; i < 4; ++i) {
            __builtin_amdgcn_global_load_lds(
                (const __attribute__((address_space(1))) unsigned int*)(aPtr + (long)i * 8 * N_ROWS),
                (__attribute__((address_space(3))) unsigned int*)(As + (i * 256 + tid) * 4),
                16, 0, 0);
        }
        #pragma unroll
        for (int i = 0; i < 4; ++i) {
            __builtin_amdgcn_global_load_lds(
                (const __attribute__((address_space(1))) unsigned int*)(bPtr + (long)i * 8 * KCODES),
                (__attribute__((address_space(3))) unsigned int*)(Bs + (i * 256 + tid) * 4),
                16, 0, 0);
        }
        __syncthreads();
        aPtr += (long)BK * N_ROWS;
        bPtr += (long)BK * KCODES;
        // ---- compute: 8x8 micro-tile; operands born as f32x2 (ds_read_b64)
        #pragma unroll 8
        for (int kk = 0; kk < BK; ++kk) {
            f32x2 ap[4], bp[4];
            ap[0] = *(const f32x2*)&As[kk * 128 + ty * 8];
            ap[1] = *(const f32x2*)&As[kk * 128 + ty * 8 + 2];
            ap[2] = *(const f32x2*)&As[kk * 128 + ty * 8 + 4];
            ap[3] = *(const f32x2*)&As[kk * 128 + ty * 8 + 6];
            bp[0] = *(const f32x2*)&Bs[kk * 128 + tx * 4];
            bp[1] = *(const f32x2*)&Bs[kk * 128 + tx * 4 + 2];
            bp[2] = *(const f32x2*)&Bs[kk * 128 + 64 + tx * 4];
            bp[3] = *(const f32x2*)&Bs[kk * 128 + 64 + tx * 4 + 2];
            #pragma unroll
            for (int ih = 0; ih < 4; ++ih) {
                #pragma unroll
                for (int jp = 0; jp < 4; ++jp) {
                    asm("v_pk_fma_f32 %0, %1, %2, %0 op_sel:[0,0,0] op_sel_hi:[1,0,1]"
                        : "+v"(acc2[2 * ih][jp]) : "v"(bp[jp]), "v"(ap[ih]));
                    asm("v_pk_fma_f32 %0, %1, %2, %0 op_sel:[0,1,0] op_sel_hi:[1,1,1]"
                        : "+v"(acc2[2 * ih + 1][jp]) : "v"(bp[jp]), "v"(ap[ih]));
                }
            }
        }
    }
    // ---- epilogue: scores + per-ct candidate + deterministic global merge
    float4 en0 = *(const float4*)&enorm[ct * BNT + tx * 4];
    float4 en1 = *(const float4*)&enorm[ct * BNT + 64 + tx * 4];
    float en[8] = {en0.x, en0.y, en0.z, en0.w, en1.x, en1.y, en1.z, en1.w};
    int col0 = ct * BNT + tx * 4;
    int col1 = ct * BNT + 64 + tx * 4;
    #pragma unroll
    for (int i = 0; i < 8; ++i) {
        float bv = 3.4e38f;
        int bi = 0;
        #pragma unroll
        for (int j = 0; j < 8; ++j) {
            float d = (j & 1) ? acc2[i][j >> 1].y : acc2[i][j >> 1].x;
            float s = en[j] - 2.0f * d;
            int col = (j < 4) ? (col0 + j) : (col1 + (j - 4));
            if (s < bv) { bv = s; bi = col; }           // ascending cols: first-min kept
        }
        #pragma unroll
        for (int m = 1; m < 16; m <<= 1) {
            float ov = __shfl_xor(bv, m);
            int   oi = __shfl_xor(bi, m);
            if (ov < bv || (ov == bv && oi < bi)) { bv = ov; bi = oi; }
        }
        if (tx == 0) {
            float t = bv + 0.0f;                         // fold -0.0 -> +0.0
            unsigned ub = __float_as_uint(t);
            unsigned enc = (t >= 0.f) ? (ub ^ 0x80000000u) : ~ub;  // order-preserving
            unsigned long long pk = ((unsigned long long)enc << 32) | (unsigned)bi;
            atomicMin(&packed[row0 + ty * 8 + i], pk);   // lexicographic (score, idx) min
        }
    }
}

// ---------------- gather codebook rows + diff partials (8 rows/block) ----------------
__global__ void gather_out(const float* __restrict__ x, const float* __restrict__ embedT,
                           const float* __restrict__ scale, const float* __restrict__ shift,
                           const unsigned long long* __restrict__ packed, float* __restrict__ out,
                           float* __restrict__ diffPart) {
    __shared__ float wsum[4];
    int tid = threadIdx.x;
    int wave = tid >> 6, lane = tid & 63;
    int d0 = lane * 4;
    float4 sc = *(const float4*)&scale[d0];
    float4 sh = *(const float4*)&shift[d0];
    float acc = 0.f;
    #pragma unroll
    for (int r2 = 0; r2 < 2; ++r2) {
        long row = (long)blockIdx.x * 8 + wave * 2 + r2;
        int k = (int)(unsigned)(packed[row] & 0xFFFFFFFFULL);
        float4 q  = *(const float4*)&embedT[(long)k * DIM + d0];
        float4 xv = *(const float4*)&x[row * DIM + d0];
        float xn0 = xv.x * sc.x + sh.x;
        float xn1 = xv.y * sc.y + sh.y;
        float xn2 = xv.z * sc.z + sh.z;
        float xn3 = xv.w * sc.w + sh.w;
        *(float4*)&out[row * DIM + d0] = q;
        float d0f = q.x - xn0, d1f = q.y - xn1, d2f = q.z - xn2, d3f = q.w - xn3;
        float dsq = d0f * d0f + d1f * d1f + d2f * d2f + d3f * d3f;
        #pragma unroll
        for (int m = 32; m; m >>= 1) dsq += __shfl_xor(dsq, m);
        acc += dsq;
    }
    if (lane == 0) wsum[wave] = acc;
    __syncthreads();
    if (tid == 0) diffPart[blockIdx.x] = wsum[0] + wsum[1] + wsum[2] + wsum[3];
}

// ---------------- final diff reduce ----------------
__global__ void diff_final(const float* __restrict__ diffPart, float* __restrict__ outDiff) {
    __shared__ float s[256];
    int tid = threadIdx.x;
    float a = 0.f;
    for (int i = tid; i < G_BLOCKS; i += 256) a += diffPart[i];
    s[tid] = a;
    __syncthreads();
    for (int st = 128; st; st >>= 1) {
        if (tid < st) s[tid] += s[tid + st];
        __syncthreads();
    }
    if (tid == 0) outDiff[0] = s[0] * (1.0f / (float)(N_ROWS * DIM));
}

extern "C" void kernel_launch(void* const* d_in, const int* in_sizes, int n_in,
                              void* d_out, int out_size, void* d_ws, size_t ws_size,
                              hipStream_t stream) {
    const float* x     = (const float*)d_in[0];
    const float* embed = (const float*)d_in[1];
    const float* gamma = (const float*)d_in[2];
    const float* beta  = (const float*)d_in[3];
    float* out = (float*)d_out;

    // xnT (fp32, transposed, 64 MB) lives in d_out; gather rewrites it after dist.
    float* xnT = (float*)d_out;

    // ws layout — same proven extent
    char* w = (char*)d_ws;
    float* pSum    = (float*)(w);                 // [0, 512K)   bn only
    float* pSq     = (float*)(w + 524288);        // [512K, 1M)  bn only
    unsigned long long* packed = (unsigned long long*)(w);  // 512K, overlays dead pSum
    float* scale   = (float*)(w + 1048576);       // 1 KB
    float* shift   = (float*)(w + 1049600);       // 1 KB
    float* embedT  = (float*)(w + 1050624);       // 1 MB
    float* enorm   = (float*)(w + 2099200);       // 4 KB
    float* diffPart= (float*)(w + 2365440);       // 32 KB -> ends 2398208

    bn_partial<<<STAT_BLOCKS, 256, 0, stream>>>(x, pSum, pSq);
    bn_finalize<<<1, 256, 0, stream>>>(pSum, pSq, gamma, beta, scale, shift);
    prep_fused<<<32 + (N_ROWS / 64) * (DIM / 64), 256, 0, stream>>>(
        embed, embedT, enorm, packed, x, scale, shift, xnT);
    dist_ct<<<(N_ROWS / BM) * 8, 256, 0, stream>>>(xnT, embed, enorm, packed);
    gather_out<<<G_BLOCKS, 256, 0, stream>>>(x, embedT, scale, shift, packed, out, diffPart);
    diff_final<<<1, 256, 0, stream>>>(diffPart, out + (long)N_ROWS * DIM);
}